// Round 13
// baseline (8691.349 us; speedup 1.0000x reference)
//
#include <hip/hip_runtime.h>
#include <stdint.h>

using short8 = __attribute__((ext_vector_type(8))) short;
using f32x4  = __attribute__((ext_vector_type(4))) float;
typedef unsigned long long ull;

#define DEV static __device__ __forceinline__

DEV unsigned short f2bf(float f){
  unsigned u = __builtin_bit_cast(unsigned, f);
  u = (u + 0x7FFFu + ((u >> 16) & 1u)) >> 16;
  return (unsigned short)u;
}
DEV float bf2f(unsigned short v){
  return __builtin_bit_cast(float, ((unsigned)v) << 16);
}
DEV float sigm(float x){
  float e = __builtin_amdgcn_exp2f(-1.4426950408889634f * x);
  return __builtin_amdgcn_rcpf(1.0f + e);
}
DEV float tanh_(float x){
  float e = __builtin_amdgcn_exp2f(2.885390081777927f * x); // exp(2x)
  return 1.0f - 2.0f * __builtin_amdgcn_rcpf(e + 1.0f);
}
DEV void bar_lds(){
  __builtin_amdgcn_sched_barrier(0);
  asm volatile("s_waitcnt lgkmcnt(0)" ::: "memory");
  __builtin_amdgcn_s_barrier();
  __builtin_amdgcn_sched_barrier(0);
}
// enc packed-column mapping: colp -> (gate g, unit u)
DEV void colmap_e(int colp, int& g, int& u){
  int w = colp >> 7, r = colp & 127, nt = r >> 4, l = r & 15;
  g = nt >> 1; u = w*32 + ((nt & 1) << 4) + l;
}

// ---------------- aux kernels ----------------

__global__ void k_f32_to_bf16(const float* __restrict__ in, unsigned short* __restrict__ out, int n){
  int stride = gridDim.x * blockDim.x * 4;
  for (int i = (blockIdx.x * blockDim.x + threadIdx.x) * 4; i < n; i += stride){
    float4 v = *(const float4*)(in + i);
    ushort4 o4;
    o4.x = f2bf(v.x); o4.y = f2bf(v.y); o4.z = f2bf(v.z); o4.w = f2bf(v.w);
    *(ushort4*)(out + i) = o4;
  }
}

// bf16 + bf16 -> bf16 (enc sum)
__global__ void k_add_bb(const unsigned short* __restrict__ a, const unsigned short* __restrict__ b,
                         unsigned short* __restrict__ out, int n){
  int stride = gridDim.x * blockDim.x * 8;
  for (int i = (blockIdx.x * blockDim.x + threadIdx.x) * 8; i < n; i += stride){
    short8 va = *(const short8*)(a + i);
    short8 vb = *(const short8*)(b + i);
    short8 o;
    #pragma unroll
    for (int j = 0; j < 8; ++j)
      o[j] = (short)f2bf(bf2f((unsigned short)va[j]) + bf2f((unsigned short)vb[j]));
    *(short8*)(out + i) = o;
  }
}

__global__ void k_add_f32(float* __restrict__ o, const float* __restrict__ b, int n){
  int stride = gridDim.x * blockDim.x * 4;
  for (int i = (blockIdx.x * blockDim.x + threadIdx.x) * 4; i < n; i += stride){
    float4 vo = *(const float4*)(o + i);
    float4 vb = *(const float4*)(b + i);
    vo.x += vb.x; vo.y += vb.y; vo.z += vb.z; vo.w += vb.w;
    *(float4*)(o + i) = vo;
  }
}

// R5 pack: [k; r] fused, blocked K split (dec)
__global__ void k_pack(const float* __restrict__ k0, const float* __restrict__ r0,
                       const float* __restrict__ k1, const float* __restrict__ r1,
                       unsigned short* __restrict__ out, int E, int KX, int U){
  int n = 2 * E;
  int stride = gridDim.x * blockDim.x;
  for (int i = blockIdx.x * blockDim.x + threadIdx.x; i < n; i += stride){
    int d = i / E, r = i % E;
    const float* Km = d ? k1 : k0;
    const float* Rm = d ? r1 : r0;
    int j    = r & 7;  int q = r >> 3;
    int lane = q & 63; q >>= 6;
    int nt   = q & 3;  q >>= 2;
    int kt   = q % 6;  q /= 6;
    int w    = q & 3;  int wg = q >> 2;
    int k    = (w*6 + kt)*32 + ((lane >> 4) << 3) + j;
    int col  = nt * U + wg*16 + (lane & 15);
    float v  = (k < KX) ? Km[(size_t)k * (4*U) + col]
                        : Rm[(size_t)(k - KX) * (4*U) + col];
    out[i] = f2bf(v);
  }
}

// pack enc k for the xz GEMM: [dir][ct16][w4][kt4][nt4][lane][8]
__global__ void k_pack_ge(const float* __restrict__ kf, const float* __restrict__ kb,
                          unsigned short* __restrict__ out){
  int n = 2 * 524288;
  int stride = gridDim.x * blockDim.x;
  for (int i = blockIdx.x * blockDim.x + threadIdx.x; i < n; i += stride){
    int j    = i & 7;
    int lane = (i >> 3) & 63;
    int nt   = (i >> 9) & 3;
    int kt   = (i >> 11) & 3;
    int w    = (i >> 13) & 3;
    int ct   = (i >> 15) & 15;
    int dir  = i >> 19;
    int k    = (w*4 + kt)*32 + ((lane >> 4) << 3) + j;
    int colp = ct*64 + nt*16 + (lane & 15);
    int g, u; colmap_e(colp, g, u);
    const float* K = dir ? kb : kf;
    out[i] = f2bf(K[(size_t)k * 1024 + g*256 + u]);
  }
}

// pack enc r for the zero-sync recurrence: [dir][w8][kt8][nt8][lane][8]
__global__ void k_pack_re(const float* __restrict__ rf, const float* __restrict__ rb,
                          unsigned short* __restrict__ out){
  int n = 2 * 262144;
  int stride = gridDim.x * blockDim.x;
  for (int i = blockIdx.x * blockDim.x + threadIdx.x; i < n; i += stride){
    int j    = i & 7;
    int lane = (i >> 3) & 63;
    int nt   = (i >> 9) & 7;
    int kt   = (i >> 12) & 7;
    int w    = (i >> 15) & 7;
    int dir  = i >> 18;
    int k    = kt*32 + ((lane >> 4) << 3) + j;       // source h unit
    int colp = w*128 + nt*16 + (lane & 15);
    int g, u; colmap_e(colp, g, u);
    const float* R = dir ? rb : rf;
    out[i] = f2bf(R[(size_t)k * 1024 + g*256 + u]);
  }
}

// xz GEMM: xzt[dir][1024 colp][t*64 + b] (bf16) = x @ k_enc (no bias)
__global__ __launch_bounds__(256, 1)
void k_gemm_xz(const unsigned short* __restrict__ xab,
               const unsigned short* __restrict__ pBg,
               unsigned short* __restrict__ xzt){
  const int tid  = threadIdx.x;
  const int w    = tid >> 6;
  const int lane = tid & 63;
  const int ct   = blockIdx.x & 15;
  const int t    = (blockIdx.x >> 4) & 511;
  const int dir  = blockIdx.x >> 13;

  short8 bfr[4][4];
  #pragma unroll
  for (int kt = 0; kt < 4; ++kt)
    #pragma unroll
    for (int nt = 0; nt < 4; ++nt)
      bfr[kt][nt] = *(const short8*)(pBg + (size_t)((((dir*16 + ct)*4 + w)*4 + kt)*4 + nt)*512 + lane*8);

  const int arow  = lane & 15;
  const int kgrp  = (lane >> 4) * 8;
  const int rquad = (lane >> 4) * 4;

  f32x4 acc[4][4];
  #pragma unroll
  for (int mt = 0; mt < 4; ++mt)
    #pragma unroll
    for (int nt = 0; nt < 4; ++nt)
      acc[mt][nt] = (f32x4){0.f,0.f,0.f,0.f};

  #pragma unroll
  for (int kt = 0; kt < 4; ++kt){
    const int kg = (w*4 + kt)*32;
    #pragma unroll
    for (int mt = 0; mt < 4; ++mt){
      const int row = mt*16 + arow;
      short8 a = *(const short8*)(xab + ((size_t)(row*512 + t))*512 + kg + kgrp);
      #pragma unroll
      for (int nt = 0; nt < 4; ++nt)
        acc[mt][nt] = __builtin_amdgcn_mfma_f32_16x16x32_bf16(a, bfr[kt][nt], acc[mt][nt], 0, 0, 0);
    }
  }

  __shared__ float part[4][64][68];
  #pragma unroll
  for (int mt = 0; mt < 4; ++mt)
    #pragma unroll
    for (int nt = 0; nt < 4; ++nt)
      *(f32x4*)&part[w][nt*16 + arow][mt*16 + rquad] = acc[mt][nt];

  __syncthreads();

  const int cl = tid & 63;
  const int rq = (tid >> 6) * 16;
  unsigned short ov[16];
  #pragma unroll
  for (int q = 0; q < 4; ++q){
    f32x4 v = *(const f32x4*)&part[0][cl][rq + q*4];
    #pragma unroll
    for (int ww = 1; ww < 4; ++ww)
      v += *(const f32x4*)&part[ww][cl][rq + q*4];
    #pragma unroll
    for (int r = 0; r < 4; ++r) ov[q*4 + r] = f2bf(v[r]);
  }
  size_t base = ((size_t)(dir*1024 + ct*64 + cl))*32768 + (size_t)t*64 + rq;
  *(short8*)(xzt + base)     = *(short8*)&ov[0];
  *(short8*)(xzt + base + 8) = *(short8*)&ov[8];
}

// ---------------- enc recurrence: batch-split, ZERO inter-WG sync ----------------
// 8 blocks (2 dirs x 4 row-groups of 16), 512 threads (8 waves).
// Per wave: 128 packed z-cols. r K-tiles 0..3 in registers (128 VGPR);
// K-tiles 4..7 streamed per step from L2-resident pBr in 8-frag chunks.
// h broadcast via 17KB LDS, ONE LDS-only barrier per step. No global sync.
__global__ __launch_bounds__(512, 1)
void k_enc_rec(const unsigned short* __restrict__ xzt,   // [2][1024][32768] bf16
               const unsigned short* __restrict__ pBr,
               const float* __restrict__ bias_f,
               const float* __restrict__ bias_b,
               const int*   __restrict__ sizes,
               unsigned short* __restrict__ out_f,       // [64][512][256] bf16
               unsigned short* __restrict__ out_b){
  constexpr int T = 512;
  const int tid   = threadIdx.x;
  const int w     = tid >> 6;        // 0..7
  const int lane  = tid & 63;
  const int l15   = lane & 15;
  const int kgrp  = (lane >> 4) << 3;
  const int dir   = (int)blockIdx.x >> 2;
  const int rbase = ((int)blockIdx.x & 3) * 16;

  const unsigned short* pBw = pBr + (size_t)(dir*8 + w) * 32768;  // [kt8][nt8][lane][8]

  // K-tiles 0..3 resident in registers (128 VGPR)
  short8 bfr[4][8];
  #pragma unroll
  for (int kt = 0; kt < 4; ++kt)
    #pragma unroll
    for (int nt = 0; nt < 8; ++nt)
      bfr[kt][nt] = *(const short8*)(pBw + (size_t)(kt*8 + nt)*512 + lane*8);

  const float* bias = dir ? bias_b : bias_f;
  unsigned short* outp = dir ? out_b : out_f;

  float bz[2][4];
  #pragma unroll
  for (int us = 0; us < 2; ++us){
    const int u = w*32 + us*16 + l15;
    #pragma unroll
    for (int g = 0; g < 4; ++g) bz[us][g] = bias[g*256 + u];
  }
  int sz[4];
  #pragma unroll
  for (int r2 = 0; r2 < 4; ++r2) sz[r2] = sizes[rbase + (lane >> 4)*4 + r2];

  float c[2][4], hv[2][4];
  #pragma unroll
  for (int us = 0; us < 2; ++us)
    #pragma unroll
    for (int r2 = 0; r2 < 4; ++r2){ c[us][r2] = 0.f; hv[us][r2] = 0.f; }

  __shared__ unsigned short hl[2][16][264];   // [parity][row][unit + pad]
  for (int i = tid; i < 16*264; i += 512) ((unsigned short*)hl[0])[i] = 0;
  __syncthreads();

  const size_t xzdir = (size_t)dir * 1024 * 32768;

  // xz prefetch for step 0
  ushort4 xv[8];
  {
    const int t0 = dir ? T - 1 : 0;
    #pragma unroll
    for (int nt = 0; nt < 8; ++nt){
      const int colp = w*128 + nt*16 + l15;
      xv[nt] = *(const ushort4*)(xzt + xzdir + (size_t)colp*32768 + (size_t)t0*64 + rbase + ((lane >> 4) << 2));
    }
  }

  for (int s = 0; s < T; ++s){
    const int t   = dir ? (T - 1 - s) : s;
    const int par = s & 1;

    // acc init = xz (prefetched)
    f32x4 acc[8];
    #pragma unroll
    for (int nt = 0; nt < 8; ++nt)
      acc[nt] = (f32x4){bf2f(xv[nt].x), bf2f(xv[nt].y), bf2f(xv[nt].z), bf2f(xv[nt].w)};

    // h @ r, register K-tiles 0..3
    #pragma unroll
    for (int kt = 0; kt < 4; ++kt){
      short8 a = *(const short8*)&hl[par][l15][kt*32 + kgrp];
      #pragma unroll
      for (int nt = 0; nt < 8; ++nt)
        acc[nt] = __builtin_amdgcn_mfma_f32_16x16x32_bf16(a, bfr[kt][nt], acc[nt], 0, 0, 0);
    }
    // h @ r, streamed K-tiles 4..7 (8-frag chunks from L2)
    #pragma unroll
    for (int skt = 0; skt < 4; ++skt){
      const int kt = 4 + skt;
      short8 sf0 = *(const short8*)(pBw + (size_t)(kt*8 + 0)*512 + lane*8);
      short8 sf1 = *(const short8*)(pBw + (size_t)(kt*8 + 1)*512 + lane*8);
      short8 sf2 = *(const short8*)(pBw + (size_t)(kt*8 + 2)*512 + lane*8);
      short8 sf3 = *(const short8*)(pBw + (size_t)(kt*8 + 3)*512 + lane*8);
      short8 sf4 = *(const short8*)(pBw + (size_t)(kt*8 + 4)*512 + lane*8);
      short8 sf5 = *(const short8*)(pBw + (size_t)(kt*8 + 5)*512 + lane*8);
      short8 sf6 = *(const short8*)(pBw + (size_t)(kt*8 + 6)*512 + lane*8);
      short8 sf7 = *(const short8*)(pBw + (size_t)(kt*8 + 7)*512 + lane*8);
      short8 a = *(const short8*)&hl[par][l15][kt*32 + kgrp];
      acc[0] = __builtin_amdgcn_mfma_f32_16x16x32_bf16(a, sf0, acc[0], 0, 0, 0);
      acc[1] = __builtin_amdgcn_mfma_f32_16x16x32_bf16(a, sf1, acc[1], 0, 0, 0);
      acc[2] = __builtin_amdgcn_mfma_f32_16x16x32_bf16(a, sf2, acc[2], 0, 0, 0);
      acc[3] = __builtin_amdgcn_mfma_f32_16x16x32_bf16(a, sf3, acc[3], 0, 0, 0);
      acc[4] = __builtin_amdgcn_mfma_f32_16x16x32_bf16(a, sf4, acc[4], 0, 0, 0);
      acc[5] = __builtin_amdgcn_mfma_f32_16x16x32_bf16(a, sf5, acc[5], 0, 0, 0);
      acc[6] = __builtin_amdgcn_mfma_f32_16x16x32_bf16(a, sf6, acc[6], 0, 0, 0);
      acc[7] = __builtin_amdgcn_mfma_f32_16x16x32_bf16(a, sf7, acc[7], 0, 0, 0);
    }

    // gate math: thread owns 2 units x 4 rows (all 4 gates in-thread)
    #pragma unroll
    for (int us = 0; us < 2; ++us){
      const int u = w*32 + us*16 + l15;
      #pragma unroll
      for (int r2 = 0; r2 < 4; ++r2){
        float ig = sigm (acc[0 + us][r2] + bz[us][0]);
        float fg = sigm (acc[2 + us][r2] + bz[us][1]);
        float gg = tanh_(acc[4 + us][r2] + bz[us][2]);
        float og = sigm (acc[6 + us][r2] + bz[us][3]);
        float cn = fg * c[us][r2] + ig * gg;
        float hn = og * tanh_(cn);
        bool m = (t < sz[r2]);
        c[us][r2] = m ? cn : c[us][r2];
        float h = m ? hn : hv[us][r2];
        hv[us][r2] = h;
        unsigned short hb16 = f2bf(h);
        const int rloc = (lane >> 4)*4 + r2;
        hl[par ^ 1][rloc][u] = hb16;
        outp[((size_t)((rbase + rloc)*512) + t)*256 + u] = hb16;
      }
    }

    // xz prefetch for next step (overlaps barrier + next h-MFMAs)
    if (s != T - 1){
      const int tn = dir ? t - 1 : t + 1;
      #pragma unroll
      for (int nt = 0; nt < 8; ++nt){
        const int colp = w*128 + nt*16 + l15;
        xv[nt] = *(const ushort4*)(xzt + xzdir + (size_t)colp*32768 + (size_t)tn*64 + rbase + ((lane >> 4) << 2));
      }
    }

    bar_lds();   // h(par^1) visible to all waves
  }
}

// ---------------- R5 persistent recurrence (dec) ----------------
template<int KX, int U, int WGS>
__global__ __launch_bounds__(256, 1)
void lstm_rec(const unsigned short* __restrict__ xab,
              const unsigned short* __restrict__ packedB,
              const float* __restrict__ bias_f,
              const float* __restrict__ bias_b,
              const int*   __restrict__ sizes,
              unsigned short* __restrict__ hbuf,
              unsigned int*  __restrict__ counters,
              float* __restrict__ out_f,
              float* __restrict__ out_b)
{
  constexpr int KTW = 6;
  constexpr int T   = 512;

  const int tid  = threadIdx.x;
  const int w    = tid >> 6;
  const int lane = tid & 63;
  const int dir  = (blockIdx.x >= WGS) ? 1 : 0;
  const int wg   = dir ? (int)blockIdx.x - WGS : (int)blockIdx.x;

  const unsigned short* pB = packedB + (size_t)dir * ((size_t)WGS*4*KTW*4*512)
                                     + (size_t)((wg*4 + w)*KTW)*4*512;
  unsigned short* hb  = hbuf + (size_t)dir * (2*64*U);
  unsigned int*   cnt = counters + dir * 32;
  const float* bias = dir ? bias_b : bias_f;
  float* outp       = dir ? out_b : out_f;

  const bool has_h = ((w*KTW + KTW - 1) * 32) >= KX;

  short8 bfr[KTW][4];
  #pragma unroll
  for (int kt = 0; kt < KTW; ++kt)
    #pragma unroll
    for (int nt = 0; nt < 4; ++nt)
      bfr[kt][nt] = *(const short8*)(pB + ((kt*4 + nt)*512) + lane*8);

  const int u_l = tid & 15;
  const int rb  = (tid >> 4) * 4;
  const int ug  = wg*16 + u_l;
  float bz[4]; int sz[4];
  #pragma unroll
  for (int g = 0; g < 4; ++g) bz[g] = bias[g*U + ug];
  #pragma unroll
  for (int r = 0; r < 4; ++r) sz[r] = sizes[rb + r];
  float c[4]    = {0.f,0.f,0.f,0.f};
  float hreg[4] = {0.f,0.f,0.f,0.f};

  __shared__ float part[4][64][68];

  const int arow  = lane & 15;
  const int kgrp  = (lane >> 4) * 8;
  const int rquad = (lane >> 4) * 4;

  short8 xreg[KTW][4];
  {
    const int t0 = dir ? T - 1 : 0;
    #pragma unroll
    for (int kt = 0; kt < KTW; ++kt){
      const int kg = (w*KTW + kt) * 32;
      if (kg < KX){
        #pragma unroll
        for (int mt = 0; mt < 4; ++mt)
          xreg[kt][mt] = *(const short8*)(xab + ((size_t)((mt*16 + arow)*T + t0))*KX + (kg + kgrp));
      }
    }
  }

  for (int s = 0; s < T; ++s){
    const int t   = dir ? (T - 1 - s) : s;
    const int par = s & 1;

    f32x4 acc[4][4];
    #pragma unroll
    for (int mt = 0; mt < 4; ++mt)
      #pragma unroll
      for (int nt = 0; nt < 4; ++nt)
        acc[mt][nt] = (f32x4){0.f, 0.f, 0.f, 0.f};

    #pragma unroll
    for (int kt = 0; kt < KTW; ++kt){
      const int kg = (w*KTW + kt) * 32;
      if (kg < KX){
        #pragma unroll
        for (int mt = 0; mt < 4; ++mt)
          #pragma unroll
          for (int nt = 0; nt < 4; ++nt)
            acc[mt][nt] = __builtin_amdgcn_mfma_f32_16x16x32_bf16(xreg[kt][mt], bfr[kt][nt], acc[mt][nt], 0, 0, 0);
      }
    }

    if (s > 0 && has_h){
      const unsigned tgt = (unsigned)WGS * (unsigned)s;
      for (;;){
        unsigned v = __hip_atomic_load(cnt, __ATOMIC_RELAXED, __HIP_MEMORY_SCOPE_AGENT);
        if (v >= tgt) break;
        __builtin_amdgcn_s_sleep(1);
      }
      __builtin_amdgcn_sched_barrier(0);
      #pragma unroll
      for (int kt = 0; kt < KTW; ++kt){
        const int kg = (w*KTW + kt) * 32;
        if (kg >= KX){
          #pragma unroll
          for (int mt = 0; mt < 4; ++mt){
            const ull* hp = (const ull*)
                (hb + (size_t)par*64*U + (size_t)(mt*16 + arow)*U + (kg - KX + kgrp));
            ulonglong2 u;
            u.x = __hip_atomic_load(hp,     __ATOMIC_RELAXED, __HIP_MEMORY_SCOPE_AGENT);
            u.y = __hip_atomic_load(hp + 1, __ATOMIC_RELAXED, __HIP_MEMORY_SCOPE_AGENT);
            short8 a = __builtin_bit_cast(short8, u);
            #pragma unroll
            for (int nt = 0; nt < 4; ++nt)
              acc[mt][nt] = __builtin_amdgcn_mfma_f32_16x16x32_bf16(a, bfr[kt][nt], acc[mt][nt], 0, 0, 0);
          }
        }
      }
    }

    #pragma unroll
    for (int mt = 0; mt < 4; ++mt)
      #pragma unroll
      for (int nt = 0; nt < 4; ++nt)
        *(f32x4*)&part[w][nt*16 + arow][mt*16 + rquad] = acc[mt][nt];

    __syncthreads();

    f32x4 zg[4];
    #pragma unroll
    for (int g = 0; g < 4; ++g){
      const int cb = g*16 + u_l;
      f32x4 v = *(const f32x4*)&part[0][cb][rb];
      #pragma unroll
      for (int ww = 1; ww < 4; ++ww)
        v += *(const f32x4*)&part[ww][cb][rb];
      zg[g] = v;
    }

    #pragma unroll
    for (int r = 0; r < 4; ++r){
      float ig = sigm (zg[0][r] + bz[0]);
      float fg = sigm (zg[1][r] + bz[1]);
      float gg = tanh_(zg[2][r] + bz[2]);
      float og = sigm (zg[3][r] + bz[3]);
      float cn = fg * c[r] + ig * gg;
      float hn = og * tanh_(cn);
      bool m  = (t < sz[r]);
      c[r] = m ? cn : c[r];
      float h = m ? hn : hreg[r];
      hreg[r] = h;
      __hip_atomic_store(&hb[(size_t)(par ^ 1)*64*U + (size_t)(rb + r)*U + ug],
                         (unsigned short)f2bf(h),
                         __ATOMIC_RELAXED, __HIP_MEMORY_SCOPE_AGENT);
    }

    __syncthreads();

    if (s != T - 1){
      if (tid == 0) atomicAdd(cnt, 1u);
    }

    #pragma unroll
    for (int r = 0; r < 4; ++r)
      outp[((size_t)(rb + r)*T + t)*U + ug] = hreg[r];

    if (s != T - 1){
      const int tn = dir ? t - 1 : t + 1;
      #pragma unroll
      for (int kt = 0; kt < KTW; ++kt){
        const int kg = (w*KTW + kt) * 32;
        if (kg < KX){
          #pragma unroll
          for (int mt = 0; mt < 4; ++mt)
            xreg[kt][mt] = *(const short8*)(xab + ((size_t)((mt*16 + arow)*T + tn))*KX + (kg + kgrp));
        }
      }
    }
  }
}

// ---------------- launch ----------------

extern "C" void kernel_launch(void* const* d_in, const int* in_sizes, int n_in,
                              void* d_out, int out_size, void* d_ws, size_t ws_size,
                              hipStream_t stream){
  const float* x      = (const float*)d_in[0];
  const int*   sizes  = (const int*)  d_in[1];
  const float* enc_kf = (const float*)d_in[2];
  const float* enc_rf = (const float*)d_in[3];
  const float* enc_bf = (const float*)d_in[4];
  const float* enc_kb = (const float*)d_in[5];
  const float* enc_rb = (const float*)d_in[6];
  const float* enc_bb = (const float*)d_in[7];
  const float* dec_kf = (const float*)d_in[8];
  const float* dec_rf = (const float*)d_in[9];
  const float* dec_bf = (const float*)d_in[10];
  const float* dec_kb = (const float*)d_in[11];
  const float* dec_rb = (const float*)d_in[12];
  const float* dec_bb = (const float*)d_in[13];
  float* out = (float*)d_out;
  char*  ws  = (char*)d_ws;

  // ---- aliased layout, total 170,917,888 B (ws_size >= 194,392,064 known) ----
  // phase A (gemm+enc):  [0,134.2M)=xzt  [134.2M,167.8M)=xbf  [167.8M,169.9M)=pBg
  //                      [169.9M,170.9M)=pBr ; ehf/ehb alias xbf after gemm
  // phase B (dec):       inside dead xzt: esum, pBd, hbufd, cntd, hbd
  const size_t o_xzt  = 0;                         // 134,217,728
  const size_t o_xbf  = 134217728ull;              //  33,554,432
  const size_t o_pBg  = o_xbf + 33554432ull;       //   2,097,152
  const size_t o_pBr  = o_pBg + 2097152ull;        //   1,048,576
  const size_t TOTAL  = o_pBr + 1048576ull;        // 170,917,888

  const size_t o_ehf  = o_xbf;                     // alias xbf (dead after gemm)
  const size_t o_ehb  = o_ehf + 16777216ull;       // ends exactly at xbf end

  const size_t o_esum  = 0;                        // alias xzt (dead after enc_rec)
  const size_t o_pBd   = o_esum + 16777216ull;
  const size_t o_hbufd = o_pBd  + 6291456ull;
  const size_t o_cntd  = o_hbufd + 262144ull;
  const size_t o_hbd   = o_cntd + 4096ull;         // ends at 90,447,872 < 134M

  if (ws_size < TOTAL) return;

  unsigned short* xzt  = (unsigned short*)(ws + o_xzt);
  unsigned short* xbf  = (unsigned short*)(ws + o_xbf);
  unsigned short* pBg  = (unsigned short*)(ws + o_pBg);
  unsigned short* pBr  = (unsigned short*)(ws + o_pBr);
  unsigned short* ehf  = (unsigned short*)(ws + o_ehf);
  unsigned short* ehb  = (unsigned short*)(ws + o_ehb);
  unsigned short* esum = (unsigned short*)(ws + o_esum);
  unsigned short* pBd  = (unsigned short*)(ws + o_pBd);
  unsigned short* hbufd= (unsigned short*)(ws + o_hbufd);
  unsigned int*   cntd = (unsigned int*)(ws + o_cntd);
  float*          hbd  = (float*)(ws + o_hbd);

  // ---- phase A: enc ----
  k_f32_to_bf16<<<2048, 256, 0, stream>>>(x, xbf, 64*512*512);
  k_pack_ge<<<1024, 256, 0, stream>>>(enc_kf, enc_kb, pBg);
  k_pack_re<<<512, 256, 0, stream>>>(enc_rf, enc_rb, pBr);

  // xz = x @ k_enc (both dirs), transposed bf16
  k_gemm_xz<<<16384, 256, 0, stream>>>(xbf, pBg, xzt);
  // zero-sync batch-split enc recurrence (xbf dead; ehf/ehb alias it)
  k_enc_rec<<<8, 512, 0, stream>>>(xzt, pBr, enc_bf, enc_bb, sizes, ehf, ehb);

  // ---- phase B: dec (xzt dead; esum/pBd/hbufd/cntd/hbd alias it) ----
  hipMemsetAsync(ws + o_cntd, 0, 4096ull, stream);
  k_pack<<<2048, 256, 0, stream>>>(dec_kf, dec_rf, dec_kb, dec_rb, pBd, 1572864, 256, 512);
  k_add_bb<<<2048, 256, 0, stream>>>(ehf, ehb, esum, 64*512*256);

  lstm_rec<256, 512, 32><<<64, 256, 0, stream>>>(esum, pBd, dec_bf, dec_bb, sizes,
                                                 hbufd, cntd, out, hbd);
  k_add_f32<<<2048, 256, 0, stream>>>(out, hbd, 64*512*512);
}